// Round 1
// baseline (850.843 us; speedup 1.0000x reference)
//
#include <hip/hip_runtime.h>
#include <hip/hip_bf16.h>

// Row-wise inclusive prefix sum (cumsum along axis 1) for a 4096 x 32768 fp32
// matrix. One 256-thread block per row; each iteration scans a 1024-element
// chunk with float4 loads, per-thread 4-elem scan, wave64 shuffle scan,
// cross-wave LDS combine, and a running carry across chunks.

#define ROW_LEN   32768
#define BLOCK     256
#define WAVES     (BLOCK / 64)
#define CHUNK     (BLOCK * 4)               // 1024 floats per iteration
#define NITERS    (ROW_LEN / CHUNK)         // 32

__global__ __launch_bounds__(BLOCK) void cumsum_rows_kernel(
    const float* __restrict__ in, float* __restrict__ out)
{
    const int row  = blockIdx.x;
    const int tid  = threadIdx.x;
    const int lane = tid & 63;
    const int wave = tid >> 6;

    const float4* in4  = reinterpret_cast<const float4*>(in  + (size_t)row * ROW_LEN);
    float4*       out4 = reinterpret_cast<float4*>(      out + (size_t)row * ROW_LEN);

    __shared__ float wave_sums[WAVES];

    float carry = 0.0f;

    #pragma unroll 1
    for (int it = 0; it < NITERS; ++it) {
        float4 v = in4[it * BLOCK + tid];

        // in-register inclusive scan of the 4 elements
        v.y += v.x;
        v.z += v.y;
        v.w += v.z;
        const float tsum = v.w;

        // wave-level inclusive scan of per-thread sums (64 lanes)
        float s = tsum;
        #pragma unroll
        for (int off = 1; off < 64; off <<= 1) {
            float t = __shfl_up(s, off, 64);
            if (lane >= off) s += t;
        }

        // publish per-wave totals
        if (lane == 63) wave_sums[wave] = s;
        __syncthreads();

        // offset from preceding waves in this chunk
        float wave_off = 0.0f;
        #pragma unroll
        for (int w = 0; w < WAVES; ++w) {
            float ws = wave_sums[w];
            if (w < wave) wave_off += ws;
        }
        // total of this chunk (for the carry update)
        float total = 0.0f;
        #pragma unroll
        for (int w = 0; w < WAVES; ++w) total += wave_sums[w];

        const float excl = (s - tsum) + wave_off + carry;
        v.x += excl;
        v.y += excl;
        v.z += excl;
        v.w += excl;

        out4[it * BLOCK + tid] = v;

        carry += total;
        __syncthreads();   // protect wave_sums before next iteration's write
    }
}

extern "C" void kernel_launch(void* const* d_in, const int* in_sizes, int n_in,
                              void* d_out, int out_size, void* d_ws, size_t ws_size,
                              hipStream_t stream)
{
    const float* x = (const float*)d_in[0];
    float* out = (float*)d_out;

    const int n_rows = out_size / ROW_LEN;   // 4096

    cumsum_rows_kernel<<<n_rows, BLOCK, 0, stream>>>(x, out);
}